// Round 6
// baseline (176.732 us; speedup 1.0000x reference)
//
#include <hip/hip_runtime.h>
#include <hip/hip_bf16.h>

#define N_ATOMS 512
#define CDIM 64
#define NSIG 16384
#define KS 4
#define NBINS 33
#define NS_BLK 16   // signals per fused block (8 waves; GEMM: 2 wave-groups x 8 signals; OMP: 2 signals/wave, hand-paired)

// ws layout (floats): [0,32768) Dn[c][n] ; [32768,65536) DnT[n][c] ;
// [65536,327680) G[n][n]
#define WS_DN   0
#define WS_DNT  32768
#define WS_G    65536
#define LOSS_IDX (NSIG * CDIM)

// k_normalize also zero-inits the loss slot for the fused kernel's atomics.
__global__ void k_normalize(const float* __restrict__ dict,
                            float* __restrict__ Dn, float* __restrict__ DnT,
                            float* __restrict__ out) {
    const int n = blockIdx.x;    // atom/column
    const int c = threadIdx.x;   // channel/row (64 threads = 1 wave)
    float v = dict[c * N_ATOMS + n];
    float sq = v * v;
    #pragma unroll
    for (int off = 32; off > 0; off >>= 1) sq += __shfl_down(sq, off);
    sq = __shfl(sq, 0);
    float m = fmaxf(sqrtf(sq), 1e-10f);
    float r = v / m;             // division to match reference exactly
    Dn[c * N_ATOMS + n] = r;
    DnT[n * CDIM + c]  = r;
    if (n == 0 && c == 0) out[LOSS_IDX] = 0.f;
}

__global__ void k_gram(const float* __restrict__ Dn, float* __restrict__ G) {
    __shared__ float sc[CDIM];
    const int i = blockIdx.x;
    const int t = threadIdx.x;
    if (t < CDIM) sc[t] = Dn[t * N_ATOMS + i];
    __syncthreads();
    for (int j = t; j < N_ATOMS; j += 256) {
        float a = 0.f;
        #pragma unroll
        for (int c = 0; c < CDIM; c++) a = fmaf(sc[c], Dn[c * N_ATOMS + j], a);
        G[i * N_ATOMS + j] = a;
    }
}

// 8-way select, VALUE-passed (pointer-escape of register arrays sends them
// to scratch — round-4 lesson). e wave-uniform; 7-cndmask tree.
__device__ __forceinline__ float sel8v(float f0, float f1, float f2, float f3,
                                       float f4, float f5, float f6, float f7,
                                       int e) {
    float x0 = (e & 1) ? f1 : f0;
    float x1 = (e & 1) ? f3 : f2;
    float x2 = (e & 1) ? f5 : f4;
    float x3 = (e & 1) ? f7 : f6;
    float y0 = (e & 2) ? x1 : x0;
    float y1 = (e & 2) ? x3 : x2;
    return (e & 4) ? y1 : y0;
}
#define SEL8(arr, e) sel8v(arr[0], arr[1], arr[2], arr[3], \
                           arr[4], arr[5], arr[6], arr[7], e)

// Fused v10: NS_BLK=16, hand-paired 2-signal OMP (chains genuinely overlap:
// both butterflies / row loads / extraction shuffles issued back-to-back per
// step), k-vectorized GEMM via DnT b128 + 2 atoms/lane (4x fewer loop iters,
// 2x fewer LDS broadcasts per FMA). Per-(signal,atom) arithmetic order
// identical to v7/v9 -> tokens/zste bit-identical.
__global__ __launch_bounds__(512, 4) void k_fused7(
    const float* __restrict__ z, const float* __restrict__ DnT,
    const float* __restrict__ G, float* __restrict__ out)
{
    __shared__ float Xs[CDIM][NS_BLK];      // [c][s] 4 KB
    __shared__ float Hs[NS_BLK][516];       // hbar tile 33 KB; reused for zste
    __shared__ float tk[NS_BLK][KS];
    __shared__ float lred[NS_BLK];
    const int t = threadIdx.x;
    const int wave = t >> 6, lane = t & 63;
    const int s0 = blockIdx.x * NS_BLK;
    const int b = s0 >> 10;
    const int hw0 = s0 & 1023;

    if (t < 256) {   // coalesced z stage: c = t>>2, signals f..f+3 (f = (t&3)*4)
        const int c = t >> 2, f = (t & 3) * 4;
        float4 v = *(const float4*)(z + (b * CDIM + c) * 1024 + hw0 + f);
        Xs[c][f + 0] = v.x; Xs[c][f + 1] = v.y;
        Xs[c][f + 2] = v.z; Xs[c][f + 3] = v.w;
    }
    __syncthreads();

    {   // GEMM: group g = wave>>2 -> signals 8g..8g+7; wl = wave&3 -> atoms
        // [wl*128,+128); lane owns atoms n0 and n0+64. DnT rows are contiguous
        // in k -> b128 loads; kc/kk ascending keeps k-ascending fmaf order.
        const int g = wave >> 2, wl = wave & 3;
        const int n0 = wl * 128 + lane;
        const float* dApt = DnT + n0 * CDIM;
        const float* dBpt = DnT + (n0 + 64) * CDIM;
        float acc[8][2];
        #pragma unroll
        for (int q = 0; q < 8; q++) { acc[q][0] = 0.f; acc[q][1] = 0.f; }
        for (int kc = 0; kc < CDIM; kc += 4) {
            float4 da = *(const float4*)(dApt + kc);
            float4 db = *(const float4*)(dBpt + kc);
            const float a4[4] = {da.x, da.y, da.z, da.w};
            const float b4[4] = {db.x, db.y, db.z, db.w};
            #pragma unroll
            for (int kk = 0; kk < 4; kk++) {
                float4 x0 = *(const float4*)(&Xs[kc + kk][g * 8]);
                float4 x1 = *(const float4*)(&Xs[kc + kk][g * 8 + 4]);
                const float xs[8] = {x0.x, x0.y, x0.z, x0.w,
                                     x1.x, x1.y, x1.z, x1.w};
                #pragma unroll
                for (int q = 0; q < 8; q++) {
                    acc[q][0] = fmaf(xs[q], a4[kk], acc[q][0]);
                    acc[q][1] = fmaf(xs[q], b4[kk], acc[q][1]);
                }
            }
        }
        #pragma unroll
        for (int q = 0; q < 8; q++) {
            Hs[g * 8 + q][n0]      = acc[q][0];
            Hs[g * 8 + q][n0 + 64] = acc[q][1];
        }
    }
    __syncthreads();

    // OMP: wave pairs signals slA=2w, slB=2w+1 through ONE k-loop so the two
    // dependent chains (shuffle butterflies, G-row loads, extractions) overlap.
    {
        const int slA = wave * 2, slB = slA + 1;
        const float xchA = Xs[lane][slA], xchB = Xs[lane][slB];

        float hbA[8], hbB[8];
        *(float4*)(&hbA[0]) = *(const float4*)(&Hs[slA][lane * 8]);
        *(float4*)(&hbA[4]) = *(const float4*)(&Hs[slA][lane * 8 + 4]);
        *(float4*)(&hbB[0]) = *(const float4*)(&Hs[slB][lane * 8]);
        *(float4*)(&hbB[4]) = *(const float4*)(&Hs[slB][lane * 8 + 4]);

        float hA[8], hB[8];
        #pragma unroll
        for (int j = 0; j < 8; j++) { hA[j] = hbA[j]; hB[j] = hbB[j]; }

        unsigned selA = 0, selB = 0;
        float LA[KS][KS], LB[KS][KS], invA[KS], invB[KS], hsA[KS], hsB[KS];
        float rA[KS - 1][8], rB[KS - 1][8];
        int IA[KS], IB[KS]; float cfA[KS], cfB[KS];
        LA[0][0] = 1.f; invA[0] = 1.f; LB[0][0] = 1.f; invB[0] = 1.f;

        #pragma unroll
        for (int k = 0; k < KS; k++) {
            // lane-local argmax (lowest-j tie-break), both signals
            float bvA = -1.f, bvB = -1.f; int bnA = N_ATOMS, bnB = N_ATOMS;
            #pragma unroll
            for (int j = 0; j < 8; j++) {
                float vA = (selA & (1u << j)) ? 0.f : fabsf(hA[j]);
                if (vA > bvA) { bvA = vA; bnA = lane * 8 + j; }
                float vB = (selB & (1u << j)) ? 0.f : fabsf(hB[j]);
                if (vB > bvB) { bvB = vB; bnB = lane * 8 + j; }
            }
            // interleaved xor-butterfly max: the two chains overlap
            float wmA = bvA, wmB = bvB;
            #pragma unroll
            for (int off = 32; off > 0; off >>= 1) {
                float tA = __shfl_xor(wmA, off);
                float tB = __shfl_xor(wmB, off);
                wmA = fmaxf(wmA, tA); wmB = fmaxf(wmB, tB);
            }
            const int winA = (int)__ffsll(__ballot(bvA == wmA)) - 1;
            const int winB = (int)__ffsll(__ballot(bvB == wmB)) - 1;
            const int idxA = __shfl(bnA, winA);
            const int idxB = __shfl(bnB, winB);
            if ((idxA >> 3) == lane) selA |= 1u << (idxA & 7);
            if ((idxB >> 3) == lane) selB |= 1u << (idxB & 7);
            const int ownA = idxA >> 3, eA = idxA & 7;
            const int ownB = idxB >> 3, eB = idxB & 7;

            if (k < KS - 1) {   // both row loads in flight together
                const float4* ga = (const float4*)(G + idxA * N_ATOMS + lane * 8);
                const float4* gb = (const float4*)(G + idxB * N_ATOMS + lane * 8);
                float4 a0 = ga[0], a1 = ga[1], b0 = gb[0], b1 = gb[1];
                rA[k][0] = a0.x; rA[k][1] = a0.y; rA[k][2] = a0.z; rA[k][3] = a0.w;
                rA[k][4] = a1.x; rA[k][5] = a1.y; rA[k][6] = a1.z; rA[k][7] = a1.w;
                rB[k][0] = b0.x; rB[k][1] = b0.y; rB[k][2] = b0.z; rB[k][3] = b0.w;
                rB[k][4] = b1.x; rB[k][5] = b1.y; rB[k][6] = b1.z; rB[k][7] = b1.w;
            }

            if (k > 0) {
                float wA[KS - 1], wB[KS - 1];
                #pragma unroll
                for (int i2 = 0; i2 < k; i2++) {
                    float tA = __shfl(SEL8(rA[i2], eA), ownA);  // G[IA[i2]][idxA]
                    float tB = __shfl(SEL8(rB[i2], eB), ownB);
                    #pragma unroll
                    for (int j2 = 0; j2 < i2; j2++) {
                        tA -= LA[i2][j2] * wA[j2];
                        tB -= LB[i2][j2] * wB[j2];
                    }
                    wA[i2] = tA * invA[i2]; wB[i2] = tB * invB[i2];
                }
                float ssA = 0.f, ssB = 0.f;
                #pragma unroll
                for (int j2 = 0; j2 < k; j2++) {
                    ssA += wA[j2] * wA[j2]; ssB += wB[j2] * wB[j2];
                }
                float cnA = sqrtf(fmaxf(1.f - ssA, 1e-12f));
                float cnB = sqrtf(fmaxf(1.f - ssB, 1e-12f));
                #pragma unroll
                for (int j2 = 0; j2 < k; j2++) {
                    LA[k][j2] = wA[j2]; LB[k][j2] = wB[j2];
                }
                LA[k][k] = cnA; invA[k] = 1.f / cnA;
                LB[k][k] = cnB; invB[k] = 1.f / cnB;
            }
            IA[k] = idxA; IB[k] = idxB;
            hsA[k] = __shfl(SEL8(hbA, eA), ownA);   // hbar[idx], same bits
            hsB[k] = __shfl(SEL8(hbB, eB), ownB);

            float yA[KS], yB[KS];
            #pragma unroll
            for (int i2 = 0; i2 <= k; i2++) {
                float tA = hsA[i2], tB = hsB[i2];
                #pragma unroll
                for (int j2 = 0; j2 < i2; j2++) {
                    tA -= LA[i2][j2] * yA[j2]; tB -= LB[i2][j2] * yB[j2];
                }
                yA[i2] = tA * invA[i2]; yB[i2] = tB * invB[i2];
            }
            #pragma unroll
            for (int i2 = k; i2 >= 0; i2--) {
                float tA = yA[i2], tB = yB[i2];
                #pragma unroll
                for (int j2 = i2 + 1; j2 <= k; j2++) {
                    tA -= LA[j2][i2] * cfA[j2]; tB -= LB[j2][i2] * cfB[j2];
                }
                cfA[i2] = tA * invA[i2]; cfB[i2] = tB * invB[i2];
            }

            if (k < KS - 1) {
                float aA[8], aB[8];
                #pragma unroll
                for (int j = 0; j < 8; j++) { aA[j] = 0.f; aB[j] = 0.f; }
                #pragma unroll
                for (int m = 0; m <= k; m++) {
                    float cmA = cfA[m], cmB = cfB[m];
                    #pragma unroll
                    for (int j = 0; j < 8; j++) {
                        aA[j] = fmaf(cmA, rA[m][j], aA[j]);
                        aB[j] = fmaf(cmB, rB[m][j], aB[j]);
                    }
                }
                #pragma unroll
                for (int j = 0; j < 8; j++) {
                    hA[j] = hbA[j] - aA[j]; hB[j] = hbB[j] - aB[j];
                }
            }
        }

        // binning + tokens (identical arithmetic), both signals
        int tokA[KS], tokB[KS]; float cqA[KS], cqB[KS];
        #pragma unroll
        for (int j = 0; j < KS; j++) {
            float c2 = fminf(fmaxf(cfA[j], -2.f), 2.f);
            float bf = (c2 + 2.f) / 4.f * 32.f;
            int bin = (int)rintf(bf);
            bin = bin < 0 ? 0 : (bin > 32 ? 32 : bin);
            cqA[j] = -2.f + 0.125f * (float)bin;
            tokA[j] = IA[j] * NBINS + bin;
            float c2b = fminf(fmaxf(cfB[j], -2.f), 2.f);
            float bfb = (c2b + 2.f) / 4.f * 32.f;
            int binb = (int)rintf(bfb);
            binb = binb < 0 ? 0 : (binb > 32 ? 32 : binb);
            cqB[j] = -2.f + 0.125f * (float)binb;
            tokB[j] = IB[j] * NBINS + binb;
        }
        float zqA = 0.f, zqB = 0.f;
        #pragma unroll
        for (int j = 0; j < KS; j++) {
            zqA = fmaf(cqA[j], DnT[IA[j] * CDIM + lane], zqA);
            zqB = fmaf(cqB[j], DnT[IB[j] * CDIM + lane], zqB);
        }

        float dA = zqA - xchA, dB = zqB - xchB;
        Hs[slA][lane] = xchA + (zqA - xchA);   // zste overlay (row reads done)
        Hs[slB][lane] = xchB + (zqB - xchB);

        float sqA = dA * dA, sqB = dB * dB;
        #pragma unroll
        for (int off = 32; off > 0; off >>= 1) {
            sqA += __shfl_down(sqA, off);
            sqB += __shfl_down(sqB, off);
        }
        if (lane == 0) { lred[slA] = sqA; lred[slB] = sqB; }
        if (lane < KS) {
            tk[slA][lane] = (float)tokA[lane];
            tk[slB][lane] = (float)tokB[lane];
        }
    }
    __syncthreads();

    if (t < 256) {   // coalesced zste write: c = t>>2, signals f..f+3
        const int c = t >> 2, f = (t & 3) * 4;
        float4 v;
        v.x = Hs[f + 0][c]; v.y = Hs[f + 1][c];
        v.z = Hs[f + 2][c]; v.w = Hs[f + 3][c];
        *(float4*)(out + (b * CDIM + c) * 1024 + hw0 + f) = v;
    }
    if (t < NS_BLK * KS)   // 64 consecutive token floats
        out[NSIG * CDIM + 1 + s0 * KS + t] = tk[t >> 2][t & 3];
    if (t == 0) {          // one pre-scaled atomic per block; 1.25/2^20 exact
        float bl = 0.f;
        #pragma unroll
        for (int q = 0; q < NS_BLK; q++) bl += lred[q];
        atomicAdd(out + LOSS_IDX, bl * (1.25f / 1048576.f));
    }
}

extern "C" void kernel_launch(void* const* d_in, const int* in_sizes, int n_in,
                              void* d_out, int out_size, void* d_ws, size_t ws_size,
                              hipStream_t stream) {
    const float* z    = (const float*)d_in[0];
    const float* dict = (const float*)d_in[1];
    float* out  = (float*)d_out;
    float* w    = (float*)d_ws;
    float* Dn   = w + WS_DN;
    float* DnT  = w + WS_DNT;
    float* G    = w + WS_G;

    hipLaunchKernelGGL(k_normalize, dim3(N_ATOMS), dim3(CDIM), 0, stream,
                       dict, Dn, DnT, out);
    hipLaunchKernelGGL(k_gram,      dim3(N_ATOMS), dim3(256),  0, stream, Dn, G);
    hipLaunchKernelGGL(k_fused7,    dim3(NSIG / NS_BLK), dim3(512), 0, stream,
                       z, DnT, G, out);
}

// Round 7
// 111.236 us; speedup vs baseline: 1.5888x; 1.5888x over previous
//
#include <hip/hip_runtime.h>
#include <hip/hip_bf16.h>

#define N_ATOMS 512
#define CDIM 64
#define NSIG 16384
#define KS 4
#define NBINS 33
#define NS_BLK 8    // signals per fused block (8 waves; wave = 64 atoms in GEMM, 1 signal in OMP)

// ws layout (floats): [0,32768) Dn[c][n] ; [32768,65536) DnT[n][c] ;
// [65536,327680) G[n][n]
#define WS_DN   0
#define WS_DNT  32768
#define WS_G    65536
#define LOSS_IDX (NSIG * CDIM)

// k_normalize also zero-inits the loss slot for the fused kernel's atomics.
__global__ void k_normalize(const float* __restrict__ dict,
                            float* __restrict__ Dn, float* __restrict__ DnT,
                            float* __restrict__ out) {
    const int n = blockIdx.x;    // atom/column
    const int c = threadIdx.x;   // channel/row (64 threads = 1 wave)
    float v = dict[c * N_ATOMS + n];
    float sq = v * v;
    #pragma unroll
    for (int off = 32; off > 0; off >>= 1) sq += __shfl_down(sq, off);
    sq = __shfl(sq, 0);
    float m = fmaxf(sqrtf(sq), 1e-10f);
    float r = v / m;             // division to match reference exactly
    Dn[c * N_ATOMS + n] = r;
    DnT[n * CDIM + c]  = r;
    if (n == 0 && c == 0) out[LOSS_IDX] = 0.f;
}

__global__ void k_gram(const float* __restrict__ Dn, float* __restrict__ G) {
    __shared__ float sc[CDIM];
    const int i = blockIdx.x;
    const int t = threadIdx.x;
    if (t < CDIM) sc[t] = Dn[t * N_ATOMS + i];
    __syncthreads();
    for (int j = t; j < N_ATOMS; j += 256) {
        float a = 0.f;
        #pragma unroll
        for (int c = 0; c < CDIM; c++) a = fmaf(sc[c], Dn[c * N_ATOMS + j], a);
        G[i * N_ATOMS + j] = a;
    }
}

// 8-way select, VALUE-passed (pointer-escape of register arrays sends them
// to scratch — round-4 lesson). e wave-uniform; 7-cndmask tree.
__device__ __forceinline__ float sel8v(float f0, float f1, float f2, float f3,
                                       float f4, float f5, float f6, float f7,
                                       int e) {
    float x0 = (e & 1) ? f1 : f0;
    float x1 = (e & 1) ? f3 : f2;
    float x2 = (e & 1) ? f5 : f4;
    float x3 = (e & 1) ? f7 : f6;
    float y0 = (e & 2) ? x1 : x0;
    float y1 = (e & 2) ? x3 : x2;
    return (e & 4) ? y1 : y0;
}
#define SEL8(arr, e) sel8v(arr[0], arr[1], arr[2], arr[3], \
                           arr[4], arr[5], arr[6], arr[7], e)

// DPP max step: v = max(v, v shifted by ctrl). bound_ctrl=1 -> OOB lanes
// contribute +0.0f, safe because all reduced values are >= 0. Pure VALU
// (~4 cy) vs ds_bpermute (~40-120 cy) per level.
#define DPPMAX(v, ctrl)                                                     \
    v = fmaxf(v, __int_as_float(__builtin_amdgcn_update_dpp(                \
            0, __float_as_int(v), (ctrl), 0xf, 0xf, true)))

// readlane broadcast of a float from a wave-uniform lane (replaces
// __shfl with uniform src: v_readlane_b32 instead of ds_bpermute).
__device__ __forceinline__ float rdlane_f(float v, int lane) {
    return __int_as_float(__builtin_amdgcn_readlane(__float_as_int(v), lane));
}

// OMP body v11 = v9 with the cross-lane chain moved off the LDS crossbar:
//  - wave max via DPP row_shr 1/2/4/8 + row_bcast 15/31 (exact fmaxf ->
//    same max bits as the butterfly), readlane(63) broadcast;
//  - winner = lowest lane with bv==wm (ballot+ffs, unchanged tie-break:
//    lane-major atom order + per-lane lowest-j = global lowest index);
//  - all uniform-source shuffles (idx, G scalars, hbar[idx]) via readlane.
//  Selection/coeff arithmetic identical -> tokens/zste bit-identical.
__device__ __forceinline__ void omp_body(
    const float hb[8], const float* __restrict__ G, int lane,
    int I[KS], float coef[KS])
{
    float h[8];
    #pragma unroll
    for (int j = 0; j < 8; j++) h[j] = hb[j];

    unsigned sel = 0;
    float L[KS][KS];
    float hsel[KS];
    float inv[KS];
    float r[KS - 1][8];                 // kept G-row fragments (registers)
    L[0][0] = 1.f; inv[0] = 1.f;

    #pragma unroll
    for (int k = 0; k < KS; k++) {
        // lane-local argmax of |where(selected, 0, h)|, lowest-j tie-break
        float bv = -1.f; int bn = N_ATOMS;
        #pragma unroll
        for (int j = 0; j < 8; j++) {
            float v = (sel & (1u << j)) ? 0.f : fabsf(h[j]);
            if (v > bv) { bv = v; bn = lane * 8 + j; }
        }
        // wave max in lane 63 via DPP (VALU-speed), then SGPR broadcast
        float wv = bv;
        DPPMAX(wv, 0x111);   // row_shr:1
        DPPMAX(wv, 0x112);   // row_shr:2
        DPPMAX(wv, 0x114);   // row_shr:4
        DPPMAX(wv, 0x118);   // row_shr:8
        DPPMAX(wv, 0x142);   // row_bcast:15
        DPPMAX(wv, 0x143);   // row_bcast:31
        const float wm = rdlane_f(wv, 63);
        const int win = (int)__ffsll(__ballot(bv == wm)) - 1; // lowest lane
        const int idx = __builtin_amdgcn_readlane(bn, win);
        if ((idx >> 3) == lane) sel |= 1u << (idx & 7);
        const int owner = idx >> 3, e = idx & 7;

        if (k < KS - 1) {   // load row I[k]=idx early; latency hides under solves
            const float4* gr = (const float4*)(G + idx * N_ATOMS + lane * 8);
            float4 g0 = gr[0], g1 = gr[1];
            r[k][0] = g0.x; r[k][1] = g0.y; r[k][2] = g0.z; r[k][3] = g0.w;
            r[k][4] = g1.x; r[k][5] = g1.y; r[k][6] = g1.z; r[k][7] = g1.w;
        }

        if (k > 0) {
            float w[KS - 1];
            #pragma unroll
            for (int i2 = 0; i2 < k; i2++) {
                float t = rdlane_f(SEL8(r[i2], e), owner);  // G[I[i2]][idx]
                #pragma unroll
                for (int j2 = 0; j2 < i2; j2++) t -= L[i2][j2] * w[j2];
                w[i2] = t * inv[i2];
            }
            float ssum = 0.f;
            #pragma unroll
            for (int j2 = 0; j2 < k; j2++) ssum += w[j2] * w[j2];
            float corner = sqrtf(fmaxf(1.f - ssum, 1e-12f));
            #pragma unroll
            for (int j2 = 0; j2 < k; j2++) L[k][j2] = w[j2];
            L[k][k] = corner;
            inv[k] = 1.f / corner;
        }
        I[k] = idx;
        hsel[k] = rdlane_f(SEL8(hb, e), owner);   // hbar[idx], same bits

        float y[KS];
        #pragma unroll
        for (int i2 = 0; i2 <= k; i2++) {
            float t = hsel[i2];
            #pragma unroll
            for (int j2 = 0; j2 < i2; j2++) t -= L[i2][j2] * y[j2];
            y[i2] = t * inv[i2];
        }
        #pragma unroll
        for (int i2 = k; i2 >= 0; i2--) {
            float t = y[i2];
            #pragma unroll
            for (int j2 = i2 + 1; j2 <= k; j2++) t -= L[j2][i2] * coef[j2];
            coef[i2] = t * inv[i2];
        }

        if (k < KS - 1) {
            float a[8];
            #pragma unroll
            for (int j = 0; j < 8; j++) a[j] = 0.f;
            #pragma unroll
            for (int m = 0; m <= k; m++) {
                float cm = coef[m];
                #pragma unroll
                for (int j = 0; j < 8; j++) a[j] = fmaf(cm, r[m][j], a[j]);
            }
            #pragma unroll
            for (int j = 0; j < 8; j++) h[j] = hb[j] - a[j];
        }
    }
}

// Fused v11: v9 skeleton (512 thr, 1 signal/wave, register-resident rows)
// with the DS-free OMP chain. GEMM/staging/epilogue byte-identical to v9.
__global__ __launch_bounds__(512, 3) void k_fused8(
    const float* __restrict__ z, const float* __restrict__ Dn,
    const float* __restrict__ DnT, const float* __restrict__ G,
    float* __restrict__ out)
{
    __shared__ float Xs[CDIM][NS_BLK];      // [c][s] 2 KB
    __shared__ float Hs[NS_BLK][516];       // hbar tile 16.5 KB; reused for zste
    __shared__ float tk[NS_BLK][4];
    __shared__ float lred[NS_BLK];
    const int t = threadIdx.x;
    const int wave = t >> 6, lane = t & 63;
    const int s0 = blockIdx.x * NS_BLK;
    const int b = s0 >> 10;
    const int hw0 = s0 & 1023;

    if (t < 128) {   // coalesced z stage: c = t>>1, signals f..f+3 (f = (t&1)*4)
        const int c = t >> 1, f = (t & 1) * 4;
        float4 v = *(const float4*)(z + (b * CDIM + c) * 1024 + hw0 + f);
        Xs[c][f + 0] = v.x; Xs[c][f + 1] = v.y;
        Xs[c][f + 2] = v.z; Xs[c][f + 3] = v.w;
    }
    __syncthreads();

    {   // GEMM: wave owns atoms [wave*64, +64); lane owns 1 atom.
        // k-ascending fmaf per (signal, atom) — bit-identical to prior rounds.
        const int n0 = wave * 64 + lane;
        float acc[NS_BLK];
        #pragma unroll
        for (int q = 0; q < NS_BLK; q++) acc[q] = 0.f;
        for (int k = 0; k < CDIM; k++) {
            const float d = Dn[k * N_ATOMS + n0];
            float4 xlo = *(const float4*)(&Xs[k][0]);
            float4 xhi = *(const float4*)(&Xs[k][4]);
            const float xs[NS_BLK] = {xlo.x, xlo.y, xlo.z, xlo.w,
                                      xhi.x, xhi.y, xhi.z, xhi.w};
            #pragma unroll
            for (int q = 0; q < NS_BLK; q++)
                acc[q] = fmaf(xs[q], d, acc[q]);
        }
        #pragma unroll
        for (int q = 0; q < NS_BLK; q++) Hs[q][n0] = acc[q];
    }
    __syncthreads();

    // OMP: one signal per wave (sl = wave). 8 independent chains per block.
    {
        const int sl = wave;
        const float xch = Xs[lane][sl];

        float hb[8];
        *(float4*)(&hb[0]) = *(const float4*)(&Hs[sl][lane * 8]);
        *(float4*)(&hb[4]) = *(const float4*)(&Hs[sl][lane * 8 + 4]);

        int I[KS]; float coef[KS];
        omp_body(hb, G, lane, I, coef);

        int tok[KS]; float cq[KS];
        #pragma unroll
        for (int j = 0; j < KS; j++) {
            float c2 = fminf(fmaxf(coef[j], -2.f), 2.f);
            float bf = (c2 + 2.f) / 4.f * 32.f;
            int bin = (int)rintf(bf);
            bin = bin < 0 ? 0 : (bin > 32 ? 32 : bin);
            cq[j] = -2.f + 0.125f * (float)bin;
            tok[j] = I[j] * NBINS + bin;
        }
        float zq = 0.f;
        #pragma unroll
        for (int j = 0; j < KS; j++)
            zq = fmaf(cq[j], DnT[I[j] * CDIM + lane], zq);

        float diff = zq - xch;
        Hs[sl][lane] = xch + (zq - xch);   // zste overlay (row sl read is done)

        float sq = diff * diff;
        #pragma unroll
        for (int off = 32; off > 0; off >>= 1) sq += __shfl_down(sq, off);
        if (lane == 0) lred[sl] = sq;
        if (lane < KS) tk[sl][lane] = (float)tok[lane];
    }
    __syncthreads();

    if (t < 128) {   // coalesced zste write: c = t>>1, signals f..f+3
        const int c = t >> 1, f = (t & 1) * 4;
        float4 v;
        v.x = Hs[f + 0][c]; v.y = Hs[f + 1][c];
        v.z = Hs[f + 2][c]; v.w = Hs[f + 3][c];
        *(float4*)(out + (b * CDIM + c) * 1024 + hw0 + f) = v;
    }
    if (t < NS_BLK * KS)   // 32 consecutive token floats
        out[NSIG * CDIM + 1 + s0 * KS + t] = tk[t >> 2][t & 3];
    if (t == 0) {          // one pre-scaled atomic per block; 1.25/2^20 exact
        float bl = 0.f;
        #pragma unroll
        for (int q = 0; q < NS_BLK; q++) bl += lred[q];
        atomicAdd(out + LOSS_IDX, bl * (1.25f / 1048576.f));
    }
}

extern "C" void kernel_launch(void* const* d_in, const int* in_sizes, int n_in,
                              void* d_out, int out_size, void* d_ws, size_t ws_size,
                              hipStream_t stream) {
    const float* z    = (const float*)d_in[0];
    const float* dict = (const float*)d_in[1];
    float* out  = (float*)d_out;
    float* w    = (float*)d_ws;
    float* Dn   = w + WS_DN;
    float* DnT  = w + WS_DNT;
    float* G    = w + WS_G;

    hipLaunchKernelGGL(k_normalize, dim3(N_ATOMS), dim3(CDIM), 0, stream,
                       dict, Dn, DnT, out);
    hipLaunchKernelGGL(k_gram,      dim3(N_ATOMS), dim3(256),  0, stream, Dn, G);
    hipLaunchKernelGGL(k_fused8,    dim3(NSIG / NS_BLK), dim3(512), 0, stream,
                       z, Dn, DnT, G, out);
}